// Round 2
// baseline (223.494 us; speedup 1.0000x reference)
//
#include <hip/hip_runtime.h>
#include <hip/hip_fp16.h>

// ---------------- types ----------------
typedef __attribute__((ext_vector_type(8))) short short8;
typedef __attribute__((ext_vector_type(4))) float f32x4;

#define GLOBAL_AS __attribute__((address_space(1)))
#define LDS_AS __attribute__((address_space(3)))

static __device__ __forceinline__ void gload16(const void* g, void* l) {
    __builtin_amdgcn_global_load_lds((const GLOBAL_AS void*)g, (LDS_AS void*)l, 16, 0, 0);
}

// float -> bf16 RNE via bit trick
static __device__ __forceinline__ unsigned short f2bf(float f) {
    union { float f; unsigned u; } v; v.f = f;
    unsigned r = v.u + 0x7FFFu + ((v.u >> 16) & 1u);
    return (unsigned short)(r >> 16);
}

// Detect the storage dtype of ortho_vals. Legit outlier values are
// 0.01*N(0,1) rounded to f16: |v| in ~[1e-5, 0.07]. Score each
// interpretation by how many of the first 192 values land in [1e-5, 0.5].
// True fp32 -> fp32 score ~99%, fp16-read-of-fp32-bits ~20%, bf16 ~0%.
// True fp16 -> fp16 score ~99%, others ~0%. Deterministic (pure function
// of input buffer).
static __device__ int detect_vals_kind(const void* vals) {  // 0=f32 1=f16 2=bf16
    const float* f = (const float*)vals;
    const unsigned short* h = (const unsigned short*)vals;
    int s0 = 0, s1 = 0, s2 = 0;
    for (int i = 0; i < 192; ++i) {
        float a0 = fabsf(f[i]);
        if (a0 >= 1e-5f && a0 <= 0.5f) s0++;
        float a1 = fabsf(__half2float(((const __half*)vals)[i]));
        if (a1 >= 1e-5f && a1 <= 0.5f) s1++;
        union { unsigned u; float fv; } c; c.u = ((unsigned)h[i]) << 16;
        float a2 = fabsf(c.fv);
        if (a2 >= 1e-5f && a2 <= 0.5f) s2++;
    }
    if (s0 >= s1 && s0 >= s2) return 0;
    if (s1 >= s2) return 1;
    return 2;
}

// ---------------- kernel 1: dequant W (int4 packed + scale + CSR outliers) -> bf16 ----------------
__global__ __launch_bounds__(256) void dequant_w_kernel(
    const int* __restrict__ packed,      // [4096][2048] one byte value per int
    const float* __restrict__ scales,    // [4096]
    const void* __restrict__ vals,       // [nnz] dtype auto-detected
    const int* __restrict__ idxs,        // [nnz]
    const int* __restrict__ ptr,         // [4097]
    unsigned int* __restrict__ Wb)       // [4096][2048] uint = 2 bf16 (cols 2j, 2j+1)
{
    __shared__ float sp[4096];
    __shared__ int skind;
    const int row = blockIdx.x;
    for (int i = threadIdx.x; i < 4096; i += 256) sp[i] = 0.0f;
    if (threadIdx.x == 0) skind = detect_vals_kind(vals);
    __syncthreads();
    const int kind = skind;
    const int s = ptr[row], e = ptr[row + 1];
    if (kind == 0) {
        const float* vf = (const float*)vals;
        for (int i = s + threadIdx.x; i < e; i += 256)
            atomicAdd(&sp[idxs[i]], vf[i]);
    } else if (kind == 1) {
        const __half* vh = (const __half*)vals;
        for (int i = s + threadIdx.x; i < e; i += 256)
            atomicAdd(&sp[idxs[i]], __half2float(vh[i]));
    } else {
        const unsigned short* vb = (const unsigned short*)vals;
        for (int i = s + threadIdx.x; i < e; i += 256) {
            union { unsigned u; float fv; } c; c.u = ((unsigned)vb[i]) << 16;
            atomicAdd(&sp[idxs[i]], c.fv);
        }
    }
    __syncthreads();
    const float sc = scales[row];
    const int* prow = packed + (size_t)row * 2048;
    unsigned int* wrow = Wb + (size_t)row * 2048;
    for (int j = threadIdx.x; j < 2048; j += 256) {
        const int p = prow[j];
        const float lo = (float)((p & 0xF) - 8) * sc + sp[2 * j];
        const float hi = (float)(((p >> 4) & 0xF) - 8) * sc + sp[2 * j + 1];
        wrow[j] = (unsigned)f2bf(lo) | ((unsigned)f2bf(hi) << 16);
    }
}

// ---------------- kernel 2: x fp32 -> bf16 ----------------
__global__ __launch_bounds__(256) void xcast_kernel(
    const float* __restrict__ x, unsigned short* __restrict__ xb, int n8)
{
    const int stride = gridDim.x * blockDim.x;
    for (int j = blockIdx.x * blockDim.x + threadIdx.x; j < n8; j += stride) {
        const float4 a = ((const float4*)x)[2 * (size_t)j];
        const float4 b = ((const float4*)x)[2 * (size_t)j + 1];
        short8 o;
        o[0] = (short)f2bf(a.x); o[1] = (short)f2bf(a.y);
        o[2] = (short)f2bf(a.z); o[3] = (short)f2bf(a.w);
        o[4] = (short)f2bf(b.x); o[5] = (short)f2bf(b.y);
        o[6] = (short)f2bf(b.z); o[7] = (short)f2bf(b.w);
        *(short8*)(xb + 8 * (size_t)j) = o;
    }
}

// ---------------- kernel 3: C[M,N] = Xb[M,K] * Wb[N,K]^T  (bf16 MFMA, fp32 out) ----------------
// m97 structure: 128x128 tile, BK=64, 4 waves (2x2, each 64x64), global_load_lds w=16,
// XOR-swizzled LDS via pre-swizzled global source (m173 pattern).
__global__ __launch_bounds__(256) void gemm_bt_kernel(
    const unsigned short* __restrict__ A,   // bf16 bits, M x K
    const unsigned short* __restrict__ B,   // bf16 bits, N x K
    float* __restrict__ C)                  // fp32, M x N
{
    constexpr int K = 4096;
    constexpr int N = 4096;
    __shared__ unsigned short As[128 * 64];
    __shared__ unsigned short Bs[128 * 64];

    const int tid = threadIdx.x;
    const int lane = tid & 63;
    const int wv = tid >> 6;          // 0..3
    const int bid = blockIdx.x;
    const int bm = bid >> 5;          // M/128 = 32 tiles
    const int bn = bid & 31;          // N/128 = 32 tiles

    // ---- staging geometry: each gload16 round = one wave writes 8 rows x 128B ----
    const int rl = lane >> 3;                 // row within 8-row chunk, 0..7
    const int sg = (lane & 7) ^ rl;           // pre-swizzled segment (XOR swizzle)
    const unsigned short* ag = A + (size_t)(bm * 128 + wv * 8 + rl) * K + sg * 8;
    const unsigned short* bg = B + (size_t)(bn * 128 + wv * 8 + rl) * K + sg * 8;
    char* ldsA = (char*)As + (wv * 8) * 128;  // wave-uniform LDS base
    char* ldsB = (char*)Bs + (wv * 8) * 128;

    // ---- fragment read geometry ----
    const int wr = wv >> 1, wc = wv & 1;      // 2x2 wave grid
    const int rowa = wr * 64 + (lane & 15);
    const int rowb = wc * 64 + (lane & 15);
    const int x7 = lane & 7;
    const int khw = lane >> 4;                // 0..3

    f32x4 acc[4][4];
#pragma unroll
    for (int m = 0; m < 4; ++m)
#pragma unroll
        for (int n = 0; n < 4; ++n) acc[m][n] = (f32x4)0.0f;

    for (int kt = 0; kt < K; kt += 64) {
#pragma unroll
        for (int t = 0; t < 4; ++t) {
            gload16(ag + kt + t * 32 * K, ldsA + t * 32 * 128);
            gload16(bg + kt + t * 32 * K, ldsB + t * 32 * 128);
        }
        __syncthreads();   // compiler drains vmcnt(0) before s_barrier
#pragma unroll
        for (int kki = 0; kki < 2; ++kki) {
            const int sb = (((kki << 2) + khw) ^ x7) << 4;  // swizzled 16B segment
            short8 af[4], bf[4];
#pragma unroll
            for (int m = 0; m < 4; ++m)
                af[m] = *(const short8*)((const char*)As + (rowa + m * 16) * 128 + sb);
#pragma unroll
            for (int n = 0; n < 4; ++n)
                bf[n] = *(const short8*)((const char*)Bs + (rowb + n * 16) * 128 + sb);
#pragma unroll
            for (int m = 0; m < 4; ++m)
#pragma unroll
                for (int n = 0; n < 4; ++n)
                    acc[m][n] = __builtin_amdgcn_mfma_f32_16x16x32_bf16(af[m], bf[n], acc[m][n], 0, 0, 0);
        }
        __syncthreads();   // protect LDS before next stage
    }

    // ---- epilogue: C/D layout col=lane&15, row=(lane>>4)*4+reg (m89-verified) ----
    const int crow0 = bm * 128 + wr * 64 + (lane >> 4) * 4;
    const int ccol0 = bn * 128 + wc * 64 + (lane & 15);
#pragma unroll
    for (int m = 0; m < 4; ++m)
#pragma unroll
        for (int n = 0; n < 4; ++n)
#pragma unroll
            for (int r = 0; r < 4; ++r)
                C[(size_t)(crow0 + m * 16 + r) * N + ccol0 + n * 16] = acc[m][n][r];
}

// ---------------- launch ----------------
extern "C" void kernel_launch(void* const* d_in, const int* in_sizes, int n_in,
                              void* d_out, int out_size, void* d_ws, size_t ws_size,
                              hipStream_t stream) {
    const float* x        = (const float*)d_in[0];
    const int* packed     = (const int*)d_in[1];
    const float* scales   = (const float*)d_in[2];
    const void* vals      = (const void*)d_in[3];   // dtype auto-detected on device
    const int* idxs       = (const int*)d_in[4];
    const int* ptr        = (const int*)d_in[5];
    float* out            = (float*)d_out;

    unsigned short* Wb = (unsigned short*)d_ws;            // 4096*4096 bf16 = 32 MB
    unsigned short* Xb = Wb + (size_t)4096 * 4096;         // next 32 MB

    dequant_w_kernel<<<4096, 256, 0, stream>>>(packed, scales, vals, idxs, ptr, (unsigned int*)Wb);
    xcast_kernel<<<2048, 256, 0, stream>>>(x, Xb, (4096 * 4096) / 8);
    gemm_bt_kernel<<<1024, 256, 0, stream>>>(Xb, Wb, out);
}

// Round 3
// 183.654 us; speedup vs baseline: 1.2169x; 1.2169x over previous
//
#include <hip/hip_runtime.h>
#include <hip/hip_fp16.h>

// ---------------- types ----------------
typedef __attribute__((ext_vector_type(8))) short short8;
typedef __attribute__((ext_vector_type(4))) float f32x4;

#define GLOBAL_AS __attribute__((address_space(1)))
#define LDS_AS __attribute__((address_space(3)))

static __device__ __forceinline__ void gload16(const void* g, void* l) {
    __builtin_amdgcn_global_load_lds((const GLOBAL_AS void*)g, (LDS_AS void*)l, 16, 0, 0);
}

#define SBAR() __builtin_amdgcn_s_barrier()
#define WAITVM(N) asm volatile("s_waitcnt vmcnt(" #N ")" ::: "memory")

// float -> bf16 RNE via bit trick
static __device__ __forceinline__ unsigned short f2bf(float f) {
    union { float f; unsigned u; } v; v.f = f;
    unsigned r = v.u + 0x7FFFu + ((v.u >> 16) & 1u);
    return (unsigned short)(r >> 16);
}

// Detect storage dtype of ortho_vals (see round-1 notes): score fp32/fp16/bf16
// interpretations of the first 192 values against |v| in [1e-5, 0.5].
static __device__ int detect_vals_kind(const void* vals) {  // 0=f32 1=f16 2=bf16
    const float* f = (const float*)vals;
    const unsigned short* h = (const unsigned short*)vals;
    int s0 = 0, s1 = 0, s2 = 0;
    for (int i = 0; i < 192; ++i) {
        float a0 = fabsf(f[i]);
        if (a0 >= 1e-5f && a0 <= 0.5f) s0++;
        float a1 = fabsf(__half2float(((const __half*)vals)[i]));
        if (a1 >= 1e-5f && a1 <= 0.5f) s1++;
        union { unsigned u; float fv; } c; c.u = ((unsigned)h[i]) << 16;
        float a2 = fabsf(c.fv);
        if (a2 >= 1e-5f && a2 <= 0.5f) s2++;
    }
    if (s0 >= s1 && s0 >= s2) return 0;
    if (s1 >= s2) return 1;
    return 2;
}

// ---------------- kernel 1: dequant W -> bf16 (vectorized int4/uint4) ----------------
__global__ __launch_bounds__(256) void dequant_w_kernel(
    const int* __restrict__ packed,      // [4096][2048] one byte value per int
    const float* __restrict__ scales,    // [4096]
    const void* __restrict__ vals,       // [nnz] dtype auto-detected
    const int* __restrict__ idxs,        // [nnz]
    const int* __restrict__ ptr,         // [4097]
    uint4* __restrict__ Wb4)             // [4096][512] uint4 = 8 bf16
{
    __shared__ float sp[4096];
    __shared__ int skind;
    const int row = blockIdx.x;
    float4* sp4 = (float4*)sp;
    const float4 z4 = make_float4(0.f, 0.f, 0.f, 0.f);
    for (int i = threadIdx.x; i < 1024; i += 256) sp4[i] = z4;
    if (threadIdx.x == 0) skind = detect_vals_kind(vals);
    __syncthreads();
    const int kind = skind;
    const int s = ptr[row], e = ptr[row + 1];
    if (kind == 0) {
        const float* vf = (const float*)vals;
        for (int i = s + threadIdx.x; i < e; i += 256) atomicAdd(&sp[idxs[i]], vf[i]);
    } else if (kind == 1) {
        const __half* vh = (const __half*)vals;
        for (int i = s + threadIdx.x; i < e; i += 256) atomicAdd(&sp[idxs[i]], __half2float(vh[i]));
    } else {
        const unsigned short* vb = (const unsigned short*)vals;
        for (int i = s + threadIdx.x; i < e; i += 256) {
            union { unsigned u; float fv; } c; c.u = ((unsigned)vb[i]) << 16;
            atomicAdd(&sp[idxs[i]], c.fv);
        }
    }
    __syncthreads();
    const float sc = scales[row];
    const int4* prow4 = (const int4*)(packed + (size_t)row * 2048);
    uint4* wrow4 = Wb4 + (size_t)row * 512;
    for (int j = threadIdx.x; j < 512; j += 256) {   // 2 iters: 4 packed ints = 8 cols
        const int4 p = prow4[j];
        const float* spc = sp + 8 * j;
        uint4 o;
        o.x = (unsigned)f2bf((float)((p.x & 0xF) - 8) * sc + spc[0]) |
              ((unsigned)f2bf((float)(((p.x >> 4) & 0xF) - 8) * sc + spc[1]) << 16);
        o.y = (unsigned)f2bf((float)((p.y & 0xF) - 8) * sc + spc[2]) |
              ((unsigned)f2bf((float)(((p.y >> 4) & 0xF) - 8) * sc + spc[3]) << 16);
        o.z = (unsigned)f2bf((float)((p.z & 0xF) - 8) * sc + spc[4]) |
              ((unsigned)f2bf((float)(((p.z >> 4) & 0xF) - 8) * sc + spc[5]) << 16);
        o.w = (unsigned)f2bf((float)((p.w & 0xF) - 8) * sc + spc[6]) |
              ((unsigned)f2bf((float)(((p.w >> 4) & 0xF) - 8) * sc + spc[7]) << 16);
        wrow4[j] = o;
    }
}

// ---------------- kernel 2: x fp32 -> bf16 ----------------
__global__ __launch_bounds__(256) void xcast_kernel(
    const float* __restrict__ x, unsigned short* __restrict__ xb, int n8)
{
    const int stride = gridDim.x * blockDim.x;
    for (int j = blockIdx.x * blockDim.x + threadIdx.x; j < n8; j += stride) {
        const float4 a = ((const float4*)x)[2 * (size_t)j];
        const float4 b = ((const float4*)x)[2 * (size_t)j + 1];
        short8 o;
        o[0] = (short)f2bf(a.x); o[1] = (short)f2bf(a.y);
        o[2] = (short)f2bf(a.z); o[3] = (short)f2bf(a.w);
        o[4] = (short)f2bf(b.x); o[5] = (short)f2bf(b.y);
        o[6] = (short)f2bf(b.z); o[7] = (short)f2bf(b.w);
        *(short8*)(xb + 8 * (size_t)j) = o;
    }
}

// ---------------- kernel 3: 256x256-tile 4-phase pipelined bf16 GEMM ----------------
// C[M,N] = A[M,K] * B[N,K]^T. 8 waves (2Mx4N), per-wave 128x64 out, BK=64,
// double-buffered 128KB LDS, counted vmcnt (full tile in flight across compute),
// raw s_barrier phases, setprio around MFMA clusters. Swizzle identical to the
// round-2 kernel (measured 0 bank conflicts).
__global__ __launch_bounds__(512, 2) void gemm_bt_kernel(
    const unsigned short* __restrict__ A,   // bf16 bits, M x K
    const unsigned short* __restrict__ B,   // bf16 bits, N x K
    float* __restrict__ C)                  // fp32, M x N
{
    constexpr int K = 4096;
    constexpr int N = 4096;
    __shared__ __attribute__((aligned(128))) char smem[131072]; // [2 buf][A 32KB | B 32KB]

    const int tid = threadIdx.x;
    const int lane = tid & 63;
    const int wv = tid >> 6;              // 0..7
    const int bm = blockIdx.x >> 4;       // 16 M-tiles
    const int bn = blockIdx.x & 15;       // 16 N-tiles

    // ---- staging geometry: one gload16 round (512 thr x 16B) = 64 rows x 128B ----
    const int grow = tid >> 3;                          // 0..63 row within round
    const int sg = (tid & 7) ^ (grow & 7);              // pre-swizzled 16B segment
    const unsigned short* ag = A + (size_t)(bm * 256 + grow) * K + sg * 8;
    const unsigned short* bg = B + (size_t)(bn * 256 + grow) * K + sg * 8;
    char* ldsw = smem + (wv * 8) * 128;                 // wave-uniform base (+lane*16 by HW)

    // round r<4: A rows r*64..r*64+63 ; r>=4: B rows (r-4)*64..
#define STAGE(R, KT, BUF)                                                              \
    {                                                                                  \
        if ((R) < 4)                                                                   \
            gload16(ag + (size_t)((R) * 64) * K + (KT),                                \
                    ldsw + (BUF) * 65536 + (R) * 64 * 128);                            \
        else                                                                           \
            gload16(bg + (size_t)(((R) - 4) * 64) * K + (KT),                          \
                    ldsw + (BUF) * 65536 + 32768 + ((R) - 4) * 64 * 128);              \
    }

    // ---- fragment read geometry ----
    const int wr = wv >> 2, wc = wv & 3;                // 2x4 wave grid
    const int rowa = wr * 128 + (lane & 15);            // + mh*64 + m*16
    const int rowb = wc * 64 + (lane & 15);             // + n*16
    const int khw = lane >> 4;                          // 0..3
    const int rx = lane & 7;                            // row&7 (row bases are mult of 8)

#define LDA4(DST, MH, KK, BUF)                                                         \
    {                                                                                  \
        _Pragma("unroll") for (int m = 0; m < 4; ++m) {                                \
            const int row_ = rowa + (MH) * 64 + m * 16;                                \
            DST[m] = *(const short8*)(smem + (BUF) * 65536 + row_ * 128 +              \
                                      (((((KK) << 2) + khw) ^ rx) << 4));              \
        }                                                                              \
    }
#define LDB4(DST, KK, BUF)                                                             \
    {                                                                                  \
        _Pragma("unroll") for (int n = 0; n < 4; ++n) {                                \
            const int row_ = rowb + n * 16;                                            \
            DST[n] = *(const short8*)(smem + (BUF) * 65536 + 32768 + row_ * 128 +      \
                                      (((((KK) << 2) + khw) ^ rx) << 4));              \
        }                                                                              \
    }
#define MFMA16(AF, BF, MH)                                                             \
    {                                                                                  \
        __builtin_amdgcn_s_setprio(1);                                                 \
        _Pragma("unroll") for (int m = 0; m < 4; ++m)                                  \
            _Pragma("unroll") for (int n = 0; n < 4; ++n)                              \
                acc[(MH) * 4 + m][n] = __builtin_amdgcn_mfma_f32_16x16x32_bf16(        \
                    AF[m], BF[n], acc[(MH) * 4 + m][n], 0, 0, 0);                      \
        __builtin_amdgcn_s_setprio(0);                                                 \
    }

    f32x4 acc[8][4];
#pragma unroll
    for (int m = 0; m < 8; ++m)
#pragma unroll
        for (int n = 0; n < 4; ++n) acc[m][n] = (f32x4)0.0f;

    // ---- prologue: stage tile 0 into buf0 (8 loads in flight) ----
#pragma unroll
    for (int r = 0; r < 8; ++r) STAGE(r, 0, 0);

    constexpr int NT = K / 64;   // 64 K-tiles
    for (int t = 0; t < NT; ++t) {
        const int cur = t & 1, nxt = cur ^ 1;
        const int ktn = (t + 1) * 64;
        // tile boundary: issue first 2 rounds of next tile, then wait for CURRENT
        // tile's 8 loads (leaving the 2 new ones in flight), then sync all waves.
        if (t + 1 < NT) {
            STAGE(0, ktn, nxt); STAGE(1, ktn, nxt);
            WAITVM(2);
        } else {
            WAITVM(0);
        }
        SBAR();

        short8 af[4], bf[4];
        // ---- P0: quadrant (mh=0, kk=0) ----
        LDA4(af, 0, 0, cur); LDB4(bf, 0, cur);
        if (t + 1 < NT) { STAGE(2, ktn, nxt); STAGE(3, ktn, nxt); }
        SBAR();
        MFMA16(af, bf, 0);
        SBAR();
        // ---- P1: (mh=1, kk=0), reuse bf ----
        LDA4(af, 1, 0, cur);
        if (t + 1 < NT) { STAGE(4, ktn, nxt); STAGE(5, ktn, nxt); }
        SBAR();
        MFMA16(af, bf, 1);
        SBAR();
        // ---- P2: (mh=0, kk=1) ----
        LDA4(af, 0, 1, cur); LDB4(bf, 1, cur);
        if (t + 1 < NT) { STAGE(6, ktn, nxt); STAGE(7, ktn, nxt); }
        SBAR();
        MFMA16(af, bf, 0);
        SBAR();
        // ---- P3: (mh=1, kk=1) ----
        LDA4(af, 1, 1, cur);
        SBAR();
        MFMA16(af, bf, 1);
        SBAR();   // protects buf[cur] from next iteration's boundary stage writes
    }

    // ---- epilogue: C/D layout col=lane&15, row=(lane>>4)*4+reg ----
    const int crow0 = bm * 256 + wr * 128 + (lane >> 4) * 4;
    const int ccol0 = bn * 256 + wc * 64 + (lane & 15);
#pragma unroll
    for (int m = 0; m < 8; ++m)
#pragma unroll
        for (int n = 0; n < 4; ++n)
#pragma unroll
            for (int r = 0; r < 4; ++r)
                C[(size_t)(crow0 + m * 16 + r) * N + ccol0 + n * 16] = acc[m][n][r];
}

// ---------------- launch ----------------
extern "C" void kernel_launch(void* const* d_in, const int* in_sizes, int n_in,
                              void* d_out, int out_size, void* d_ws, size_t ws_size,
                              hipStream_t stream) {
    const float* x        = (const float*)d_in[0];
    const int* packed     = (const int*)d_in[1];
    const float* scales   = (const float*)d_in[2];
    const void* vals      = (const void*)d_in[3];   // dtype auto-detected on device
    const int* idxs       = (const int*)d_in[4];
    const int* ptr        = (const int*)d_in[5];
    float* out            = (float*)d_out;

    unsigned short* Wb = (unsigned short*)d_ws;            // 4096*4096 bf16 = 32 MB
    unsigned short* Xb = Wb + (size_t)4096 * 4096;         // next 32 MB

    dequant_w_kernel<<<4096, 256, 0, stream>>>(packed, scales, vals, idxs, ptr, (uint4*)Wb);
    xcast_kernel<<<2048, 256, 0, stream>>>(x, Xb, (4096 * 4096) / 8);
    gemm_bt_kernel<<<256, 512, 0, stream>>>(Xb, Wb, out);
}

// Round 4
// 182.982 us; speedup vs baseline: 1.2214x; 1.0037x over previous
//
#include <hip/hip_runtime.h>
#include <hip/hip_fp16.h>

// ---------------- types ----------------
typedef __attribute__((ext_vector_type(8))) short short8;
typedef __attribute__((ext_vector_type(4))) float f32x4;

#define GLOBAL_AS __attribute__((address_space(1)))
#define LDS_AS __attribute__((address_space(3)))

static __device__ __forceinline__ void gload16(const void* g, void* l) {
    __builtin_amdgcn_global_load_lds((const GLOBAL_AS void*)g, (LDS_AS void*)l, 16, 0, 0);
}

#define SBAR() __builtin_amdgcn_s_barrier()
#define WAITVM(N) asm volatile("s_waitcnt vmcnt(" #N ")" ::: "memory")

// float -> bf16 RNE via bit trick
static __device__ __forceinline__ unsigned short f2bf(float f) {
    union { float f; unsigned u; } v; v.f = f;
    unsigned r = v.u + 0x7FFFu + ((v.u >> 16) & 1u);
    return (unsigned short)(r >> 16);
}

// Detect storage dtype of ortho_vals (round-1 finding: harness delivers fp16
// refs as fp32). Score fp32/fp16/bf16 interpretations of the first 192 values
// against the known outlier range |v| in [1e-5, 0.5]. Deterministic.
static __device__ int detect_vals_kind(const void* vals) {  // 0=f32 1=f16 2=bf16
    const float* f = (const float*)vals;
    const unsigned short* h = (const unsigned short*)vals;
    int s0 = 0, s1 = 0, s2 = 0;
    for (int i = 0; i < 192; ++i) {
        float a0 = fabsf(f[i]);
        if (a0 >= 1e-5f && a0 <= 0.5f) s0++;
        float a1 = fabsf(__half2float(((const __half*)vals)[i]));
        if (a1 >= 1e-5f && a1 <= 0.5f) s1++;
        union { unsigned u; float fv; } c; c.u = ((unsigned)h[i]) << 16;
        float a2 = fabsf(c.fv);
        if (a2 >= 1e-5f && a2 <= 0.5f) s2++;
    }
    if (s0 >= s1 && s0 >= s2) return 0;
    if (s1 >= s2) return 1;
    return 2;
}

// ---------------- kernel 1: fused prep ----------------
// blocks [0,4096): dequant W row -> bf16 (int4 + scale + CSR outliers)
// blocks [4096,6144): x fp32 -> bf16 cast (grid-stride over 2M short8)
__global__ __launch_bounds__(256) void prep_kernel(
    const int* __restrict__ packed,      // [4096][2048] one byte value per int
    const float* __restrict__ scales,    // [4096]
    const void* __restrict__ vals,       // [nnz] dtype auto-detected
    const int* __restrict__ idxs,        // [nnz]
    const int* __restrict__ ptr,         // [4097]
    uint4* __restrict__ Wb4,             // [4096][512] uint4 = 8 bf16
    const float* __restrict__ x,
    unsigned short* __restrict__ xb)
{
    if (blockIdx.x >= 4096) {
        // ---- xcast branch ----
        const int n8 = (4096 * 4096) / 8;
        const int stride = 2048 * 256;
        for (int j = (blockIdx.x - 4096) * 256 + threadIdx.x; j < n8; j += stride) {
            const float4 a = ((const float4*)x)[2 * (size_t)j];
            const float4 b = ((const float4*)x)[2 * (size_t)j + 1];
            short8 o;
            o[0] = (short)f2bf(a.x); o[1] = (short)f2bf(a.y);
            o[2] = (short)f2bf(a.z); o[3] = (short)f2bf(a.w);
            o[4] = (short)f2bf(b.x); o[5] = (short)f2bf(b.y);
            o[6] = (short)f2bf(b.z); o[7] = (short)f2bf(b.w);
            *(short8*)(xb + 8 * (size_t)j) = o;
        }
        return;
    }
    // ---- dequant branch ----
    __shared__ float sp[4096];
    __shared__ int skind;
    const int row = blockIdx.x;
    float4* sp4 = (float4*)sp;
    const float4 z4 = make_float4(0.f, 0.f, 0.f, 0.f);
    for (int i = threadIdx.x; i < 1024; i += 256) sp4[i] = z4;
    if (threadIdx.x == 0) skind = detect_vals_kind(vals);
    __syncthreads();
    const int kind = skind;
    const int s = ptr[row], e = ptr[row + 1];
    if (kind == 0) {
        const float* vf = (const float*)vals;
        for (int i = s + threadIdx.x; i < e; i += 256) atomicAdd(&sp[idxs[i]], vf[i]);
    } else if (kind == 1) {
        const __half* vh = (const __half*)vals;
        for (int i = s + threadIdx.x; i < e; i += 256) atomicAdd(&sp[idxs[i]], __half2float(vh[i]));
    } else {
        const unsigned short* vb = (const unsigned short*)vals;
        for (int i = s + threadIdx.x; i < e; i += 256) {
            union { unsigned u; float fv; } c; c.u = ((unsigned)vb[i]) << 16;
            atomicAdd(&sp[idxs[i]], c.fv);
        }
    }
    __syncthreads();
    const float sc = scales[row];
    const int4* prow4 = (const int4*)(packed + (size_t)row * 2048);
    uint4* wrow4 = Wb4 + (size_t)row * 512;
    for (int j = threadIdx.x; j < 512; j += 256) {   // 2 iters: 4 packed ints = 8 cols
        const int4 p = prow4[j];
        const float* spc = sp + 8 * j;
        uint4 o;
        o.x = (unsigned)f2bf((float)((p.x & 0xF) - 8) * sc + spc[0]) |
              ((unsigned)f2bf((float)(((p.x >> 4) & 0xF) - 8) * sc + spc[1]) << 16);
        o.y = (unsigned)f2bf((float)((p.y & 0xF) - 8) * sc + spc[2]) |
              ((unsigned)f2bf((float)(((p.y >> 4) & 0xF) - 8) * sc + spc[3]) << 16);
        o.z = (unsigned)f2bf((float)((p.z & 0xF) - 8) * sc + spc[4]) |
              ((unsigned)f2bf((float)(((p.z >> 4) & 0xF) - 8) * sc + spc[5]) << 16);
        o.w = (unsigned)f2bf((float)((p.w & 0xF) - 8) * sc + spc[6]) |
              ((unsigned)f2bf((float)(((p.w >> 4) & 0xF) - 8) * sc + spc[7]) << 16);
        wrow4[j] = o;
    }
}

// ---------------- kernel 2: 256x256-tile 4-phase pipelined bf16 GEMM ----------------
// C[M,N] = A[M,K] * B[N,K]^T. 8 waves (2Mx4N), per-wave 128x64 out, BK=64,
// double-buffered 128KB LDS. Change vs round-3: ALL 8 stage rounds for tile t+1
// are issued at the tile-t boundary (full 4-phase ~1000cyc HBM cover for every
// load), and the boundary wait is vmcnt(8) — it only waits on loads issued a
// full iteration earlier (never drains fresh loads). Swizzle unchanged
// (measured 0 bank conflicts).
__global__ __launch_bounds__(512, 2) void gemm_bt_kernel(
    const unsigned short* __restrict__ A,   // bf16 bits, M x K
    const unsigned short* __restrict__ B,   // bf16 bits, N x K
    float* __restrict__ C)                  // fp32, M x N
{
    constexpr int K = 4096;
    constexpr int N = 4096;
    __shared__ __attribute__((aligned(128))) char smem[131072]; // [2 buf][A 32KB | B 32KB]

    const int tid = threadIdx.x;
    const int lane = tid & 63;
    const int wv = tid >> 6;              // 0..7
    const int bm = blockIdx.x >> 4;       // 16 M-tiles
    const int bn = blockIdx.x & 15;       // 16 N-tiles

    // ---- staging geometry: one gload16 round (512 thr x 16B) = 64 rows x 128B ----
    const int grow = tid >> 3;                          // 0..63 row within round
    const int sg = (tid & 7) ^ (grow & 7);              // pre-swizzled 16B segment
    const unsigned short* ag = A + (size_t)(bm * 256 + grow) * K + sg * 8;
    const unsigned short* bg = B + (size_t)(bn * 256 + grow) * K + sg * 8;
    char* ldsw = smem + (wv * 8) * 128;                 // wave-uniform base (+lane*16 by HW)

    // round r<4: A rows r*64..r*64+63 ; r>=4: B rows (r-4)*64..
#define STAGE(R, KT, BUF)                                                              \
    {                                                                                  \
        if ((R) < 4)                                                                   \
            gload16(ag + (size_t)((R) * 64) * K + (KT),                                \
                    ldsw + (BUF) * 65536 + (R) * 64 * 128);                            \
        else                                                                           \
            gload16(bg + (size_t)(((R) - 4) * 64) * K + (KT),                          \
                    ldsw + (BUF) * 65536 + 32768 + ((R) - 4) * 64 * 128);              \
    }

    // ---- fragment read geometry ----
    const int wr = wv >> 2, wc = wv & 3;                // 2x4 wave grid
    const int rowa = wr * 128 + (lane & 15);            // + mh*64 + m*16
    const int rowb = wc * 64 + (lane & 15);             // + n*16
    const int khw = lane >> 4;                          // 0..3
    const int rx = lane & 7;                            // row&7 (row bases are mult of 8)

#define LDA4(DST, MH, KK, BUF)                                                         \
    {                                                                                  \
        _Pragma("unroll") for (int m = 0; m < 4; ++m) {                                \
            const int row_ = rowa + (MH) * 64 + m * 16;                                \
            DST[m] = *(const short8*)(smem + (BUF) * 65536 + row_ * 128 +              \
                                      (((((KK) << 2) + khw) ^ rx) << 4));              \
        }                                                                              \
    }
#define LDB4(DST, KK, BUF)                                                             \
    {                                                                                  \
        _Pragma("unroll") for (int n = 0; n < 4; ++n) {                                \
            const int row_ = rowb + n * 16;                                            \
            DST[n] = *(const short8*)(smem + (BUF) * 65536 + 32768 + row_ * 128 +      \
                                      (((((KK) << 2) + khw) ^ rx) << 4));              \
        }                                                                              \
    }
#define MFMA16(AF, BF, MH)                                                             \
    {                                                                                  \
        __builtin_amdgcn_s_setprio(1);                                                 \
        _Pragma("unroll") for (int m = 0; m < 4; ++m)                                  \
            _Pragma("unroll") for (int n = 0; n < 4; ++n)                              \
                acc[(MH) * 4 + m][n] = __builtin_amdgcn_mfma_f32_16x16x32_bf16(        \
                    AF[m], BF[n], acc[(MH) * 4 + m][n], 0, 0, 0);                      \
        __builtin_amdgcn_s_setprio(0);                                                 \
    }

    f32x4 acc[8][4];
#pragma unroll
    for (int m = 0; m < 8; ++m)
#pragma unroll
        for (int n = 0; n < 4; ++n) acc[m][n] = (f32x4)0.0f;

    // ---- prologue: stage tile 0 into buf0 (8 loads in flight) ----
#pragma unroll
    for (int r = 0; r < 8; ++r) STAGE(r, 0, 0);

    constexpr int NT = K / 64;   // 64 K-tiles
    for (int t = 0; t < NT; ++t) {
        const int cur = t & 1, nxt = cur ^ 1;
        const int ktn = (t + 1) * 64;
        // Boundary: issue ALL of tile t+1 (safe: prior iteration's trailing SBAR
        // guarantees every wave finished reading buf[nxt]); then wait for tile
        // t's 8 loads (the 8 newest stay in flight), then sync.
        if (t + 1 < NT) {
#pragma unroll
            for (int r = 0; r < 8; ++r) STAGE(r, ktn, nxt);
            WAITVM(8);
        } else {
            WAITVM(0);
        }
        SBAR();

        short8 af[4], bf[4];
        // ---- P0: quadrant (mh=0, kk=0) ----
        LDA4(af, 0, 0, cur); LDB4(bf, 0, cur);
        SBAR();
        MFMA16(af, bf, 0);
        SBAR();
        // ---- P1: (mh=1, kk=0), reuse bf ----
        LDA4(af, 1, 0, cur);
        SBAR();
        MFMA16(af, bf, 1);
        SBAR();
        // ---- P2: (mh=0, kk=1) ----
        LDA4(af, 0, 1, cur); LDB4(bf, 1, cur);
        SBAR();
        MFMA16(af, bf, 0);
        SBAR();
        // ---- P3: (mh=1, kk=1) ----
        LDA4(af, 1, 1, cur);
        SBAR();
        MFMA16(af, bf, 1);
        SBAR();   // protects buf[cur] from next iteration's boundary stage writes
    }

    // ---- epilogue: C/D layout col=lane&15, row=(lane>>4)*4+reg ----
    const int crow0 = bm * 256 + wr * 128 + (lane >> 4) * 4;
    const int ccol0 = bn * 256 + wc * 64 + (lane & 15);
#pragma unroll
    for (int m = 0; m < 8; ++m)
#pragma unroll
        for (int n = 0; n < 4; ++n)
#pragma unroll
            for (int r = 0; r < 4; ++r)
                C[(size_t)(crow0 + m * 16 + r) * N + ccol0 + n * 16] = acc[m][n][r];
}

// ---------------- launch ----------------
extern "C" void kernel_launch(void* const* d_in, const int* in_sizes, int n_in,
                              void* d_out, int out_size, void* d_ws, size_t ws_size,
                              hipStream_t stream) {
    const float* x        = (const float*)d_in[0];
    const int* packed     = (const int*)d_in[1];
    const float* scales   = (const float*)d_in[2];
    const void* vals      = (const void*)d_in[3];   // dtype auto-detected on device
    const int* idxs       = (const int*)d_in[4];
    const int* ptr        = (const int*)d_in[5];
    float* out            = (float*)d_out;

    unsigned short* Wb = (unsigned short*)d_ws;            // 4096*4096 bf16 = 32 MB
    unsigned short* Xb = Wb + (size_t)4096 * 4096;         // next 32 MB

    prep_kernel<<<6144, 256, 0, stream>>>(packed, scales, vals, idxs, ptr,
                                          (uint4*)Wb, x, Xb);
    gemm_bt_kernel<<<256, 512, 0, stream>>>(Xb, Wb, out);
}

// Round 5
// 173.520 us; speedup vs baseline: 1.2880x; 1.0545x over previous
//
#include <hip/hip_runtime.h>
#include <hip/hip_fp16.h>

// ---------------- types ----------------
typedef __attribute__((ext_vector_type(8))) short short8;
typedef __attribute__((ext_vector_type(4))) float f32x4;

#define GLOBAL_AS __attribute__((address_space(1)))
#define LDS_AS __attribute__((address_space(3)))

static __device__ __forceinline__ void gload16(const void* g, void* l) {
    __builtin_amdgcn_global_load_lds((const GLOBAL_AS void*)g, (LDS_AS void*)l, 16, 0, 0);
}

#define SBAR() __builtin_amdgcn_s_barrier()
#define WAITVM(N) asm volatile("s_waitcnt vmcnt(" #N ")" ::: "memory")

// float -> bf16 RNE via bit trick
static __device__ __forceinline__ unsigned short f2bf(float f) {
    union { float f; unsigned u; } v; v.f = f;
    unsigned r = v.u + 0x7FFFu + ((v.u >> 16) & 1u);
    return (unsigned short)(r >> 16);
}

// Detect storage dtype of ortho_vals (round-1 finding: harness delivers fp16
// refs as fp32). Score fp32/fp16/bf16 interpretations of the first 192 values
// against the known outlier range |v| in [1e-5, 0.5]. Deterministic.
static __device__ int detect_vals_kind(const void* vals) {  // 0=f32 1=f16 2=bf16
    const float* f = (const float*)vals;
    const unsigned short* h = (const unsigned short*)vals;
    int s0 = 0, s1 = 0, s2 = 0;
    for (int i = 0; i < 192; ++i) {
        float a0 = fabsf(f[i]);
        if (a0 >= 1e-5f && a0 <= 0.5f) s0++;
        float a1 = fabsf(__half2float(((const __half*)vals)[i]));
        if (a1 >= 1e-5f && a1 <= 0.5f) s1++;
        union { unsigned u; float fv; } c; c.u = ((unsigned)h[i]) << 16;
        float a2 = fabsf(c.fv);
        if (a2 >= 1e-5f && a2 <= 0.5f) s2++;
    }
    if (s0 >= s1 && s0 >= s2) return 0;
    if (s1 >= s2) return 1;
    return 2;
}

// ---------------- kernel 1: fused prep ----------------
// blocks [0,4096): dequant W row -> bf16 (int4 + scale + CSR outliers)
// blocks [4096,6144): x fp32 -> bf16 cast (grid-stride over 2M short8)
__global__ __launch_bounds__(256) void prep_kernel(
    const int* __restrict__ packed,      // [4096][2048] one byte value per int
    const float* __restrict__ scales,    // [4096]
    const void* __restrict__ vals,       // [nnz] dtype auto-detected
    const int* __restrict__ idxs,        // [nnz]
    const int* __restrict__ ptr,         // [4097]
    uint4* __restrict__ Wb4,             // [4096][512] uint4 = 8 bf16
    const float* __restrict__ x,
    unsigned short* __restrict__ xb)
{
    if (blockIdx.x >= 4096) {
        // ---- xcast branch ----
        const int n8 = (4096 * 4096) / 8;
        const int stride = 2048 * 256;
        for (int j = (blockIdx.x - 4096) * 256 + threadIdx.x; j < n8; j += stride) {
            const float4 a = ((const float4*)x)[2 * (size_t)j];
            const float4 b = ((const float4*)x)[2 * (size_t)j + 1];
            short8 o;
            o[0] = (short)f2bf(a.x); o[1] = (short)f2bf(a.y);
            o[2] = (short)f2bf(a.z); o[3] = (short)f2bf(a.w);
            o[4] = (short)f2bf(b.x); o[5] = (short)f2bf(b.y);
            o[6] = (short)f2bf(b.z); o[7] = (short)f2bf(b.w);
            *(short8*)(xb + 8 * (size_t)j) = o;
        }
        return;
    }
    // ---- dequant branch ----
    __shared__ float sp[4096];
    __shared__ int skind;
    const int row = blockIdx.x;
    float4* sp4 = (float4*)sp;
    const float4 z4 = make_float4(0.f, 0.f, 0.f, 0.f);
    for (int i = threadIdx.x; i < 1024; i += 256) sp4[i] = z4;
    if (threadIdx.x == 0) skind = detect_vals_kind(vals);
    __syncthreads();
    const int kind = skind;
    const int s = ptr[row], e = ptr[row + 1];
    if (kind == 0) {
        const float* vf = (const float*)vals;
        for (int i = s + threadIdx.x; i < e; i += 256) atomicAdd(&sp[idxs[i]], vf[i]);
    } else if (kind == 1) {
        const __half* vh = (const __half*)vals;
        for (int i = s + threadIdx.x; i < e; i += 256) atomicAdd(&sp[idxs[i]], __half2float(vh[i]));
    } else {
        const unsigned short* vb = (const unsigned short*)vals;
        for (int i = s + threadIdx.x; i < e; i += 256) {
            union { unsigned u; float fv; } c; c.u = ((unsigned)vb[i]) << 16;
            atomicAdd(&sp[idxs[i]], c.fv);
        }
    }
    __syncthreads();
    const float sc = scales[row];
    const int4* prow4 = (const int4*)(packed + (size_t)row * 2048);
    uint4* wrow4 = Wb4 + (size_t)row * 512;
    for (int j = threadIdx.x; j < 512; j += 256) {   // 2 iters: 4 packed ints = 8 cols
        const int4 p = prow4[j];
        const float* spc = sp + 8 * j;
        uint4 o;
        o.x = (unsigned)f2bf((float)((p.x & 0xF) - 8) * sc + spc[0]) |
              ((unsigned)f2bf((float)(((p.x >> 4) & 0xF) - 8) * sc + spc[1]) << 16);
        o.y = (unsigned)f2bf((float)((p.y & 0xF) - 8) * sc + spc[2]) |
              ((unsigned)f2bf((float)(((p.y >> 4) & 0xF) - 8) * sc + spc[3]) << 16);
        o.z = (unsigned)f2bf((float)((p.z & 0xF) - 8) * sc + spc[4]) |
              ((unsigned)f2bf((float)(((p.z >> 4) & 0xF) - 8) * sc + spc[5]) << 16);
        o.w = (unsigned)f2bf((float)((p.w & 0xF) - 8) * sc + spc[6]) |
              ((unsigned)f2bf((float)(((p.w >> 4) & 0xF) - 8) * sc + spc[7]) << 16);
        wrow4[j] = o;
    }
}

// ---------------- kernel 2: 256x256-tile pipelined bf16 GEMM, 2 barriers/K-tile ----------------
// C[M,N] = A[M,K] * B[N,K]^T. 8 waves (2Mx4N), per-wave 128x64 out, BK=64,
// double-buffered 128KB LDS. Round-5 change: only TWO s_barriers per K-tile
// (buffer-ready after counted vmcnt(2); buffer-free at tile end). The whole
// tile's 24 ds_read_b128 + 64 MFMA + 6 interleaved gload_lds form one
// scheduling region the compiler software-pipelines. Counted vmcnt + per-phase
// stage interleave retained (round-4 showed boundary-burst staging is -11%).
// Hazards: every ds_read is consumed by an MFMA (compiler lgkmcnt) before the
// trailing SBAR, so next-iter gload_lds writes cannot race them; staged halves
// this iter go to buf[nxt], reads come from buf[cur].
__global__ __launch_bounds__(512, 2) void gemm_bt_kernel(
    const unsigned short* __restrict__ A,   // bf16 bits, M x K
    const unsigned short* __restrict__ B,   // bf16 bits, N x K
    float* __restrict__ C)                  // fp32, M x N
{
    constexpr int K = 4096;
    constexpr int N = 4096;
    __shared__ __attribute__((aligned(128))) char smem[131072]; // [2 buf][A 32KB | B 32KB]

    const int tid = threadIdx.x;
    const int lane = tid & 63;
    const int wv = tid >> 6;              // 0..7
    // m204 bijective XCD swizzle (256 blocks % 8 XCDs == 0): XCD x gets a
    // contiguous tile range -> 2 A-panels (4MB) resident per XCD L2.
    const int bid = (blockIdx.x & 7) * 32 + (blockIdx.x >> 3);
    const int bm = bid >> 4;              // 16 M-tiles
    const int bn = bid & 15;              // 16 N-tiles

    // ---- staging geometry: one gload16 round (512 thr x 16B) = 64 rows x 128B ----
    const int grow = tid >> 3;                          // 0..63 row within round
    const int sg = (tid & 7) ^ (grow & 7);              // pre-swizzled 16B segment
    const unsigned short* ag = A + (size_t)(bm * 256 + grow) * K + sg * 8;
    const unsigned short* bg = B + (size_t)(bn * 256 + grow) * K + sg * 8;
    char* ldsw = smem + (wv * 8) * 128;                 // wave-uniform base (+lane*16 by HW)

    // round r<4: A rows r*64..r*64+63 ; r>=4: B rows (r-4)*64..
#define STAGE(R, KT, BUF)                                                              \
    {                                                                                  \
        if ((R) < 4)                                                                   \
            gload16(ag + (size_t)((R) * 64) * K + (KT),                                \
                    ldsw + (BUF) * 65536 + (R) * 64 * 128);                            \
        else                                                                           \
            gload16(bg + (size_t)(((R) - 4) * 64) * K + (KT),                          \
                    ldsw + (BUF) * 65536 + 32768 + ((R) - 4) * 64 * 128);              \
    }

    // ---- fragment read geometry ----
    const int wr = wv >> 2, wc = wv & 3;                // 2x4 wave grid
    const int rowa = wr * 128 + (lane & 15);            // + mh*64 + m*16
    const int rowb = wc * 64 + (lane & 15);             // + n*16
    const int khw = lane >> 4;                          // 0..3
    const int rx = lane & 7;                            // row&7 (row bases are mult of 8)

#define LDA4(DST, MH, KK, BUF)                                                         \
    {                                                                                  \
        _Pragma("unroll") for (int m = 0; m < 4; ++m) {                                \
            const int row_ = rowa + (MH) * 64 + m * 16;                                \
            DST[m] = *(const short8*)(smem + (BUF) * 65536 + row_ * 128 +              \
                                      (((((KK) << 2) + khw) ^ rx) << 4));              \
        }                                                                              \
    }
#define LDB4(DST, KK, BUF)                                                             \
    {                                                                                  \
        _Pragma("unroll") for (int n = 0; n < 4; ++n) {                                \
            const int row_ = rowb + n * 16;                                            \
            DST[n] = *(const short8*)(smem + (BUF) * 65536 + 32768 + row_ * 128 +      \
                                      (((((KK) << 2) + khw) ^ rx) << 4));              \
        }                                                                              \
    }
#define MFMA16(AF, BF, MH)                                                             \
    {                                                                                  \
        __builtin_amdgcn_s_setprio(1);                                                 \
        _Pragma("unroll") for (int m = 0; m < 4; ++m)                                  \
            _Pragma("unroll") for (int n = 0; n < 4; ++n)                              \
                acc[(MH) * 4 + m][n] = __builtin_amdgcn_mfma_f32_16x16x32_bf16(        \
                    AF[m], BF[n], acc[(MH) * 4 + m][n], 0, 0, 0);                      \
        __builtin_amdgcn_s_setprio(0);                                                 \
    }

    f32x4 acc[8][4];
#pragma unroll
    for (int m = 0; m < 8; ++m)
#pragma unroll
        for (int n = 0; n < 4; ++n) acc[m][n] = (f32x4)0.0f;

    // ---- prologue: stage tile 0 into buf0 (8 loads in flight) ----
#pragma unroll
    for (int r = 0; r < 8; ++r) STAGE(r, 0, 0);

    constexpr int NT = K / 64;   // 64 K-tiles
    for (int t = 0; t < NT; ++t) {
        const int cur = t & 1, nxt = cur ^ 1;
        const int ktn = (t + 1) * 64;
        __builtin_amdgcn_sched_barrier(0);   // keep stages below prior trailing SBAR
        // Boundary: first pair of tile t+1, then wait for tile t's 8 loads
        // (the 2 fresh ones stay in flight), then one barrier -> buf[cur] ready.
        if (t + 1 < NT) {
            STAGE(0, ktn, nxt); STAGE(1, ktn, nxt);
            WAITVM(2);
        } else {
            WAITVM(0);
        }
        SBAR();

        // ---- free-running compute region (compiler pipelines reads under MFMA) ----
        short8 af0[4], af1[4], bf0[4], bf1[4];
        LDA4(af0, 0, 0, cur); LDB4(bf0, 0, cur);
        if (t + 1 < NT) { STAGE(2, ktn, nxt); STAGE(3, ktn, nxt); }
        MFMA16(af0, bf0, 0);
        LDA4(af1, 1, 0, cur);
        if (t + 1 < NT) { STAGE(4, ktn, nxt); STAGE(5, ktn, nxt); }
        MFMA16(af1, bf0, 1);
        LDA4(af0, 0, 1, cur); LDB4(bf1, 1, cur);
        if (t + 1 < NT) { STAGE(6, ktn, nxt); STAGE(7, ktn, nxt); }
        MFMA16(af0, bf1, 0);
        LDA4(af1, 1, 1, cur);
        MFMA16(af1, bf1, 1);
        SBAR();   // all waves done reading buf[cur]; next iter may overwrite it
    }

    // ---- epilogue: C/D layout col=lane&15, row=(lane>>4)*4+reg ----
    const int crow0 = bm * 256 + wr * 128 + (lane >> 4) * 4;
    const int ccol0 = bn * 256 + wc * 64 + (lane & 15);
#pragma unroll
    for (int m = 0; m < 8; ++m)
#pragma unroll
        for (int n = 0; n < 4; ++n)
#pragma unroll
            for (int r = 0; r < 4; ++r)
                C[(size_t)(crow0 + m * 16 + r) * N + ccol0 + n * 16] = acc[m][n][r];
}

// ---------------- launch ----------------
extern "C" void kernel_launch(void* const* d_in, const int* in_sizes, int n_in,
                              void* d_out, int out_size, void* d_ws, size_t ws_size,
                              hipStream_t stream) {
    const float* x        = (const float*)d_in[0];
    const int* packed     = (const int*)d_in[1];
    const float* scales   = (const float*)d_in[2];
    const void* vals      = (const void*)d_in[3];   // dtype auto-detected on device
    const int* idxs       = (const int*)d_in[4];
    const int* ptr        = (const int*)d_in[5];
    float* out            = (float*)d_out;

    unsigned short* Wb = (unsigned short*)d_ws;            // 4096*4096 bf16 = 32 MB
    unsigned short* Xb = Wb + (size_t)4096 * 4096;         // next 32 MB

    prep_kernel<<<6144, 256, 0, stream>>>(packed, scales, vals, idxs, ptr,
                                          (uint4*)Wb, x, Xb);
    gemm_bt_kernel<<<256, 512, 0, stream>>>(Xb, Wb, out);
}